// Round 20
// baseline (182.056 us; speedup 1.0000x reference)
//
#include <hip/hip_runtime.h>

// ws float layout:
//  [0:16)    sum2      [16:32)  sumsq2
//  [64:118)  w1s (w1*sc1*0.25)   [118:124) b1s ((b1*sc1+sh1)*0.25)
//  [124]     T (sum of all x)
//  [125:138) A[13] autocorrelations
//  [144:528) w2s (w2*sc2)   [528:544) b2s (b2*sc2+sh2)
#define WS_SUM2 0
#define WS_SQ2  16
#define WS_W1S  64
#define WS_B1S  118
#define WS_T    124
#define WS_A    125
#define WS_W2S  144
#define WS_B2S  528
#define WS_ZERO_N 144

#define PST 146        // per-image LDS stride (even for float2; %32=18 skew)
#define POOL_CST 30    // per-channel pooled stride (5 rows x stride 6)
#define POOL_IST 180   // per-image pooled stride (mult of 4; %32=20 skew)

#define XL_F   (16 * PST)        // 2336 floats
#define POOL_F (16 * POOL_IST)   // 2880 floats

#define FW1_ST 68                // fw1 LDS row stride (2-way bank alias = free)
#define FW1_F  (30 * FW1_ST)     // 2040 floats

// Wave-synchronous LDS fence: all hot-path communication is intra-wave
// (16 threads per image, 4 images per wave). DS ops from one wave process
// in order; waitcnt + memory clobber stops compiler reordering.
#define WSYNC() asm volatile("s_waitcnt lgkmcnt(0)" ::: "memory")

__device__ __forceinline__ float wave_sum(float v) {
#pragma unroll
  for (int off = 32; off > 0; off >>= 1) v += __shfl_down(v, off, 64);
  return v;
}

// Zero this wave's 4-image xl region (wave-local).
__device__ __forceinline__ void zero_own_xl(float* xl) {
  const int tid = threadIdx.x;
  const int wv = tid >> 6, lane = tid & 63;
  float* wxl = xl + wv * (4 * PST);
  for (int i = lane; i < 4 * PST; i += 64) wxl[i] = 0.f;
}

// Write one 16-image tile's interiors from the per-thread float4 (own image).
__device__ __forceinline__ void write_interior(float* xl, float4 v) {
  const int tid = threadIdx.x;
  const int imgl = tid >> 4;
  const int f = (tid & 15) * 4;
  const int row = f >> 3, col = f & 7;
  float* dst = xl + imgl * PST + (row + 2) * 12 + (col + 2);
  dst[0] = v.x; dst[1] = v.y; dst[2] = v.z; dst[3] = v.w;
}

// Cooperative front: conv1 (BN1 + pool-1/4 folded into w1s/b1s) + ReLU +
// meanpool2 -> pool[6][5x5 (row stride 6)] per image; each value computed once.
__device__ __forceinline__ void pooled_front_coop(const float* xl, float* pool,
                                                  const float* __restrict__ wsf) {
  const int tid = threadIdx.x;
  const int imgl = tid >> 4, l16 = tid & 15;
  const float* ibase = xl + imgl * PST;
  float* pbase = pool + imgl * POOL_IST;

#pragma unroll
  for (int k2 = 0; k2 < 2; ++k2) {
    const int p = l16 + 16 * k2;
    if (p < 25) {
      const int r = p / 5, s = p % 5;
      const float* wb = ibase + (2 * r) * 12 + 2 * s;
      float X[16];
#pragma unroll
      for (int a = 0; a < 4; ++a) {
        const float2* wr = reinterpret_cast<const float2*>(wb + a * 12);
        const float2 e0 = wr[0], e1 = wr[1];
        X[a * 4 + 0] = e0.x; X[a * 4 + 1] = e0.y;
        X[a * 4 + 2] = e1.x; X[a * 4 + 3] = e1.y;
      }
#pragma unroll
      for (int i = 0; i < 16; ++i) asm volatile("" : "+v"(X[i]));
#pragma unroll
      for (int c = 0; c < 6; ++c) {
        const float bc = wsf[WS_B1S + c];
        float acc = 0.f;
#pragma unroll
        for (int di = 0; di < 2; ++di) {
#pragma unroll
          for (int dj = 0; dj < 2; ++dj) {
            float z = bc;
#pragma unroll
            for (int u = 0; u < 3; ++u)
#pragma unroll
              for (int v = 0; v < 3; ++v)
                z = fmaf(wsf[WS_W1S + c * 9 + u * 3 + v],
                         X[(di + u) * 4 + dj + v], z);
            acc += fmaxf(z, 0.f);
          }
        }
        pbase[c * POOL_CST + r * 6 + s] = acc;  // 0.25 pre-folded
      }
    }
  }
}

__device__ __forceinline__ void load6(const float* p, float r[6]) {
  const float2* q = reinterpret_cast<const float2*>(p);
  const float2 a = q[0], b = q[1], c = q[2];
  r[0] = a.x; r[1] = a.y; r[2] = b.x; r[3] = b.y; r[4] = c.x; r[5] = c.y;
}

// Channel-per-lane conv2, rolling 2-row stencil; weights read per-channel
// from LDS (broadcast) so only ~4 weight VGPRs are live at a time.
__device__ __forceinline__ void conv2_lane_lds(const float* pool,
                                               const float* w2L,
                                               const float* b2L,
                                               float yp[16]) {
  const int tid = threadIdx.x;
  const int imgl = tid >> 4, o = tid & 15;
  const float* pbase = pool + imgl * POOL_IST;

  const float yb = b2L[o];
#pragma unroll
  for (int p = 0; p < 16; ++p) yp[p] = yb;

#pragma unroll
  for (int c = 0; c < 6; ++c) {
    const float4 wv = *reinterpret_cast<const float4*>(w2L + o * 24 + c * 4);
    const float* pcb = pbase + c * POOL_CST;
    const float w00 = wv.x, w01 = wv.y, w10 = wv.z, w11 = wv.w;
    float r[2][6];
    load6(pcb, r[0]);
#pragma unroll
    for (int i2 = 0; i2 < 4; ++i2) {
      float* top = r[i2 & 1];
      float* bot = r[(i2 + 1) & 1];
      load6(pcb + (i2 + 1) * 6, bot);
#pragma unroll
      for (int j2 = 0; j2 < 4; ++j2) {
        float acc = yp[i2 * 4 + j2];
        acc = fmaf(w00, top[j2], acc);
        acc = fmaf(w01, top[j2 + 1], acc);
        acc = fmaf(w10, bot[j2], acc);
        acc = fmaf(w11, bot[j2 + 1], acc);
        yp[i2 * 4 + j2] = acc;
      }
    }
  }
}

// ------- Kernel A: x total-sum + 13 autocorrelations (grid-strided) -------
__global__ __launch_bounds__(256) void k_stats1(
    const float* __restrict__ x, float* ws, int nblk) {
  __shared__ __align__(16) float xl[XL_F];
  __shared__ float red[4][16];
  const int tid = threadIdx.x;
  zero_own_xl(xl);

  float T = 0.f, A[13];
#pragma unroll
  for (int i = 0; i < 13; ++i) A[i] = 0.f;

  int blk = blockIdx.x;
  float4 pfx;
  if (blk < nblk)
    pfx = reinterpret_cast<const float4*>(x)[(size_t)blk * 256 + tid];
  for (; blk < nblk; blk += gridDim.x) {
    WSYNC();                   // own-wave xl writes ordered
    write_interior(xl, pfx);
    const int bn = blk + gridDim.x;
    if (bn < nblk)
      pfx = reinterpret_cast<const float4*>(x)[(size_t)bn * 256 + tid];
    WSYNC();
    const float* ib = xl + (tid >> 4) * PST;
    const int l16 = tid & 15;
#pragma unroll
    for (int k = 0; k < 4; ++k) {
      const int p = l16 + k * 16;
      const int r = p >> 3, c = p & 7;
      const float* q = ib + (r + 2) * 12 + (c + 2);
      const float xc = q[0];
      T += xc;
      A[0]  = fmaf(xc, q[0],  A[0]);
      A[1]  = fmaf(xc, q[1],  A[1]);
      A[2]  = fmaf(xc, q[2],  A[2]);
      A[3]  = fmaf(xc, q[10], A[3]);
      A[4]  = fmaf(xc, q[11], A[4]);
      A[5]  = fmaf(xc, q[12], A[5]);
      A[6]  = fmaf(xc, q[13], A[6]);
      A[7]  = fmaf(xc, q[14], A[7]);
      A[8]  = fmaf(xc, q[22], A[8]);
      A[9]  = fmaf(xc, q[23], A[9]);
      A[10] = fmaf(xc, q[24], A[10]);
      A[11] = fmaf(xc, q[25], A[11]);
      A[12] = fmaf(xc, q[26], A[12]);
    }
  }

  const int wid = tid >> 6, lane = tid & 63;
#pragma unroll
  for (int i = 0; i < 14; ++i) {
    const float v = wave_sum(i == 0 ? T : A[i - 1]);
    if (lane == 0) red[wid][i] = v;
  }
  __syncthreads();             // cross-wave, once per block
  if (tid < 14) {
    const float tot = red[0][tid] + red[1][tid] + red[2][tid] + red[3][tid];
    atomicAdd(&ws[WS_T + tid], tot);
  }
}

// -------- fold1: closed-form BN1 stats -> folded conv1 weights ------------
__global__ void k_fold1(const float* __restrict__ g1,
                        const float* __restrict__ be1,
                        const float* __restrict__ w1,
                        const float* __restrict__ b1, float* ws, float NP) {
  const int c = threadIdx.x;
  if (c >= 6) return;
  float Av[13];
#pragma unroll
  for (int i = 0; i < 13; ++i) Av[i] = ws[WS_A + i];
  const float T = ws[WS_T];
  float w[9];
#pragma unroll
  for (int k = 0; k < 9; ++k) w[k] = w1[c * 9 + k];
  float sw = 0.f;
#pragma unroll
  for (int k = 0; k < 9; ++k) sw += w[k];
  float q2 = 0.f;
#pragma unroll
  for (int k1 = 0; k1 < 9; ++k1) {
    const int u1 = k1 / 3, v1 = k1 % 3;
#pragma unroll
    for (int k2 = 0; k2 < 9; ++k2) {
      int du = k2 / 3 - u1, dv = k2 % 3 - v1;
      if (du < 0 || (du == 0 && dv < 0)) { du = -du; dv = -dv; }
      const float a = (du == 0) ? Av[dv] : Av[3 + (du - 1) * 5 + dv + 2];
      q2 = fmaf(w[k1] * w[k2], a, q2);
    }
  }
  const float b = b1[c];
  const float sum1 = sw * T + NP * b;
  const float sumsq1 = q2 + 2.f * b * sw * T + NP * b * b;
  const float mean = sum1 / NP;
  const float var = sumsq1 / NP - mean * mean;
  const float sc = g1[c] * rsqrtf(var + 1e-5f);
  const float sh = be1[c] - mean * sc;
#pragma unroll
  for (int k = 0; k < 9; ++k)
    ws[WS_W1S + c * 9 + k] = w[k] * sc * 0.25f;        // pool 1/4 folded
  ws[WS_B1S + c] = fmaf(b, sc, sh) * 0.25f;
}

// -------- fold2: BN2 stats -> folded conv2 weights (w2s/b2s) ---------------
__global__ void k_fold2(const float* __restrict__ g2,
                        const float* __restrict__ be2,
                        const float* __restrict__ w2,
                        const float* __restrict__ b2, float* ws, float inv_n) {
  __shared__ float scs[16];
  const int t = threadIdx.x;
  if (t < 16) {
    const float mean = ws[WS_SUM2 + t] * inv_n;
    const float var  = ws[WS_SQ2 + t] * inv_n - mean * mean;
    const float sc   = g2[t] * rsqrtf(var + 1e-5f);
    const float sh   = be2[t] - mean * sc;
    scs[t] = sc;
    ws[WS_B2S + t] = fmaf(b2[t], sc, sh);
  }
  __syncthreads();
  if (t < 384) ws[WS_W2S + t] = w2[t] * scs[t / 24];
}

// ------- Kernel B: conv2 output statistics (grid-strided, wave-sync) -------
__global__ __launch_bounds__(256, 4) void k_stats2(
    const float* __restrict__ x, const float* __restrict__ w2,
    const float* __restrict__ b2, float* ws, int nblk) {
  __shared__ __align__(16) float xl[XL_F];
  __shared__ __align__(16) float pool[POOL_F];
  __shared__ __align__(16) float w2L[384];
  __shared__ float b2L[16];
  __shared__ float red[4][32];
  const int tid = threadIdx.x;
  for (int d = tid; d < 384; d += 256) w2L[d] = w2[d];
  if (tid < 16) b2L[tid] = b2[tid];
  zero_own_xl(xl);
  __syncthreads();             // weights visible to all waves

  float s = 0.f, q = 0.f;

  int t = blockIdx.x;
  float4 pfx;
  if (t < nblk)
    pfx = reinterpret_cast<const float4*>(x)[(size_t)t * 256 + tid];
  for (; t < nblk; t += gridDim.x) {
    WSYNC();                   // own-wave prior phase ordered
    write_interior(xl, pfx);
    const int tn = t + gridDim.x;
    if (tn < nblk)
      pfx = reinterpret_cast<const float4*>(x)[(size_t)tn * 256 + tid];
    WSYNC();
    pooled_front_coop(xl, pool, ws);
    WSYNC();
    float yp[16];
    conv2_lane_lds(pool, w2L, b2L, yp);
#pragma unroll
    for (int p = 0; p < 16; ++p) { s += yp[p]; q = fmaf(yp[p], yp[p], q); }
  }

  // reduce: across the 4 images of this wave, then across waves, one atomic
  s += __shfl_xor(s, 16, 64); s += __shfl_xor(s, 32, 64);
  q += __shfl_xor(q, 16, 64); q += __shfl_xor(q, 32, 64);
  const int wid = tid >> 6, lane = tid & 63;
  if (lane < 16) { red[wid][lane] = s; red[wid][16 + lane] = q; }
  __syncthreads();             // cross-wave, once per block
  if (tid < 32) {
    const float tot = red[0][tid] + red[1][tid] + red[2][tid] + red[3][tid];
    atomicAdd(&ws[tid < 16 ? WS_SUM2 + tid : WS_SQ2 + tid - 16], tot);
  }
}

// ---------------- Kernel C: full forward (grid-strided, wave-sync) ---------
// LDS = 30720 B caps residency at 5 blocks/CU; no min-waves hint (natural
// ~72 VGPR, no spill). Grid 2048 = exactly 4 tiles/block (no 6-vs-7
// imbalance). Tail aliases each image's dead pooled map.
__global__ __launch_bounds__(256) void k_final(
    const float* __restrict__ x, const float* __restrict__ fw1,
    const float* __restrict__ fb1, const float* __restrict__ fw2,
    const float* __restrict__ fb2, const float* __restrict__ fw3,
    const float* __restrict__ fb3, const float* __restrict__ ws,
    float* __restrict__ out, int nblk) {
  __shared__ __align__(16) float xl[XL_F];
  __shared__ __align__(16) float pool[POOL_F];
  __shared__ __align__(16) float fw1L[FW1_F];  // [a][k], row stride 68
  __shared__ __align__(16) float w2L[384];
  __shared__ float b2L[16];

  const int tid = threadIdx.x;
  for (int d = tid; d < 1920; d += 256) {
    const int a = d >> 6, k = d & 63;
    fw1L[a * FW1_ST + k] = fw1[d];
  }
  for (int d = tid; d < 384; d += 256) w2L[d] = ws[WS_W2S + d];
  if (tid < 16) b2L[tid] = ws[WS_B2S + tid];
  zero_own_xl(xl);
  __syncthreads();             // once per block: weights + pad visible

  const int imgl = tid >> 4, al = tid & 15;
  const bool has2 = (al + 16) < 30;
  const float* ra = fw1L + al * FW1_ST;
  const float* rb = fw1L + (has2 ? (al + 16) * FW1_ST : 0);
  const float fb1a = fb1[al];
  const float fb1b = has2 ? fb1[al + 16] : 0.f;
  const float fb2a = (al < 15) ? fb2[al] : 0.f;
  const float fb3a = (al < 10) ? fb3[al] : 0.f;

  int t = blockIdx.x;
  float4 pfx;
  if (t < nblk)
    pfx = reinterpret_cast<const float4*>(x)[(size_t)t * 256 + tid];
  for (; t < nblk; t += gridDim.x) {
    WSYNC();                   // prior tile's tail LDS ops done
    write_interior(xl, pfx);
    const int tn = t + gridDim.x;
    if (tn < nblk)
      pfx = reinterpret_cast<const float4*>(x)[(size_t)tn * 256 + tid];
    WSYNC();
    pooled_front_coop(xl, pool, ws);
    WSYNC();
    float zp[16];
    conv2_lane_lds(pool, w2L, b2L, zp);

    float* ib = pool + imgl * POOL_IST;  // dead pooled map -> tail buffer

    // BN2 (folded) + ReLU + meanpool2 -> h at [0,64)
    float hq[4] = {0.f, 0.f, 0.f, 0.f};
#pragma unroll
    for (int i2 = 0; i2 < 4; ++i2)
#pragma unroll
      for (int j2 = 0; j2 < 4; ++j2)
        hq[(i2 >> 1) * 2 + (j2 >> 1)] += fmaxf(zp[i2 * 4 + j2], 0.f);
    float4 hv4;
    hv4.x = 0.25f * hq[0]; hv4.y = 0.25f * hq[1];
    hv4.z = 0.25f * hq[2]; hv4.w = 0.25f * hq[3];
    *reinterpret_cast<float4*>(ib + al * 4) = hv4;
    WSYNC();

    // FC1: lane al computes outputs {al, al+16}; weights from LDS rows
    float acc0 = fb1a;
    float acc1 = fb1b;
#pragma unroll
    for (int kk = 0; kk < 16; ++kk) {
      const float4 hv = *reinterpret_cast<const float4*>(ib + kk * 4);
      const float4 wa = *reinterpret_cast<const float4*>(ra + kk * 4);
      const float4 wb = *reinterpret_cast<const float4*>(rb + kk * 4);
      acc0 = fmaf(wa.x, hv.x, acc0); acc0 = fmaf(wa.y, hv.y, acc0);
      acc0 = fmaf(wa.z, hv.z, acc0); acc0 = fmaf(wa.w, hv.w, acc0);
      acc1 = fmaf(wb.x, hv.x, acc1); acc1 = fmaf(wb.y, hv.y, acc1);
      acc1 = fmaf(wb.z, hv.z, acc1); acc1 = fmaf(wb.w, hv.w, acc1);
    }
    ib[68 + al] = fmaxf(acc0, 0.f);                  // a1 at [68,98)
    if (has2) ib[68 + al + 16] = fmaxf(acc1, 0.f);
    WSYNC();

    // FC2 -> a2 at [101,116)  (fully unrolled, weights from global/L1)
    if (al < 15) {
      float acc = fb2a;
#pragma unroll
      for (int j = 0; j < 30; ++j)
        acc = fmaf(fw2[al * 30 + j], ib[68 + j], acc);
      ib[101 + al] = fmaxf(acc, 0.f);
    }
    WSYNC();

    // FC3 + store
    if (al < 10) {
      float acc = fb3a;
#pragma unroll
      for (int j = 0; j < 15; ++j)
        acc = fmaf(fw3[al * 15 + j], ib[101 + j], acc);
      out[(size_t)(t * 16 + imgl) * 10 + al] = acc;
    }
  }
}

extern "C" void kernel_launch(void* const* d_in, const int* in_sizes, int n_in,
                              void* d_out, int out_size, void* d_ws, size_t ws_size,
                              hipStream_t stream) {
  (void)n_in; (void)out_size; (void)ws_size;
  const float* x   = (const float*)d_in[0];
  const float* w1  = (const float*)d_in[1];
  const float* b1  = (const float*)d_in[2];
  const float* g1  = (const float*)d_in[3];
  const float* be1 = (const float*)d_in[4];
  const float* w2  = (const float*)d_in[5];
  const float* b2  = (const float*)d_in[6];
  const float* g2  = (const float*)d_in[7];
  const float* be2 = (const float*)d_in[8];
  const float* fw1 = (const float*)d_in[9];
  const float* fb1 = (const float*)d_in[10];
  const float* fw2 = (const float*)d_in[11];
  const float* fb2 = (const float*)d_in[12];
  const float* fw3 = (const float*)d_in[13];
  const float* fb3 = (const float*)d_in[14];
  float* out = (float*)d_out;
  float* ws  = (float*)d_ws;

  const int Btot = in_sizes[0] / 64;  // 131072; % 16 == 0
  const int nblk = Btot / 16;         // 8192
  const float NP1 = (float)Btot * 100.0f;
  const float inv_n2 = 1.0f / ((float)Btot * 16.0f);
  const int g1rid = nblk < 4096 ? nblk : 4096;   // 2 tiles/block exact
  const int g2rid = nblk < 1024 ? nblk : 1024;   // 8 tiles/block exact
  const int kf_grid = nblk < 2048 ? nblk : 2048; // 4 tiles/block exact

  hipMemsetAsync(ws, 0, WS_ZERO_N * sizeof(float), stream);

  k_stats1<<<g1rid, 256, 0, stream>>>(x, ws, nblk);
  k_fold1<<<1, 64, 0, stream>>>(g1, be1, w1, b1, ws, NP1);
  k_stats2<<<g2rid, 256, 0, stream>>>(x, w2, b2, ws, nblk);
  k_fold2<<<1, 512, 0, stream>>>(g2, be2, w2, b2, ws, inv_n2);
  k_final<<<kf_grid, 256, 0, stream>>>(x, fw1, fb1, fw2, fb2, fw3, fb3, ws,
                                       out, nblk);
}

// Round 21
// 147.930 us; speedup vs baseline: 1.2307x; 1.2307x over previous
//
#include <hip/hip_runtime.h>

// ws float layout:
//  [0:16)    sum2      [16:32)  sumsq2
//  [64:118)  w1s (w1*sc1*0.25)   [118:124) b1s ((b1*sc1+sh1)*0.25)
//  [124]     T (sum of all x)
//  [125:138) A[13] autocorrelations
//  [144:528) w2s (w2*sc2)   [528:544) b2s (b2*sc2+sh2)
#define WS_SUM2 0
#define WS_SQ2  16
#define WS_W1S  64
#define WS_B1S  118
#define WS_T    124
#define WS_A    125
#define WS_W2S  144
#define WS_B2S  528
#define WS_ZERO_N 144

#define PST 146        // per-image LDS stride (even for float2; %32=18 skew)
#define POOL_CST 30    // per-channel pooled stride (5 rows x stride 6)
#define POOL_IST 180   // per-image pooled stride (mult of 4; %32=20 skew)

#define XL_F   (16 * PST)        // 2336 floats
#define POOL_F (16 * POOL_IST)   // 2880 floats

#define FW1_ST 68                // fw1 LDS row stride (2-way bank alias = free)
#define FW1_F  (30 * FW1_ST)     // 2040 floats

// Wave-synchronous LDS fence: all hot-path communication is intra-wave
// (16 threads per image, 4 images per wave). DS ops from one wave process
// in order; waitcnt + memory clobber stops compiler reordering.
#define WSYNC() asm volatile("s_waitcnt lgkmcnt(0)" ::: "memory")

__device__ __forceinline__ float wave_sum(float v) {
#pragma unroll
  for (int off = 32; off > 0; off >>= 1) v += __shfl_down(v, off, 64);
  return v;
}

// Zero this wave's 4-image xl region (wave-local).
__device__ __forceinline__ void zero_own_xl(float* xl) {
  const int tid = threadIdx.x;
  const int wv = tid >> 6, lane = tid & 63;
  float* wxl = xl + wv * (4 * PST);
  for (int i = lane; i < 4 * PST; i += 64) wxl[i] = 0.f;
}

// Write one 16-image tile's interiors from the per-thread float4 (own image).
__device__ __forceinline__ void write_interior(float* xl, float4 v) {
  const int tid = threadIdx.x;
  const int imgl = tid >> 4;
  const int f = (tid & 15) * 4;
  const int row = f >> 3, col = f & 7;
  float* dst = xl + imgl * PST + (row + 2) * 12 + (col + 2);
  dst[0] = v.x; dst[1] = v.y; dst[2] = v.z; dst[3] = v.w;
}

// Cooperative front: conv1 (BN1 + pool-1/4 folded into w1s/b1s) + ReLU +
// meanpool2 -> pool[6][5x5 (row stride 6)] per image; each value computed once.
__device__ __forceinline__ void pooled_front_coop(const float* xl, float* pool,
                                                  const float* __restrict__ wsf) {
  const int tid = threadIdx.x;
  const int imgl = tid >> 4, l16 = tid & 15;
  const float* ibase = xl + imgl * PST;
  float* pbase = pool + imgl * POOL_IST;

#pragma unroll
  for (int k2 = 0; k2 < 2; ++k2) {
    const int p = l16 + 16 * k2;
    if (p < 25) {
      const int r = p / 5, s = p % 5;
      const float* wb = ibase + (2 * r) * 12 + 2 * s;
      float X[16];
#pragma unroll
      for (int a = 0; a < 4; ++a) {
        const float2* wr = reinterpret_cast<const float2*>(wb + a * 12);
        const float2 e0 = wr[0], e1 = wr[1];
        X[a * 4 + 0] = e0.x; X[a * 4 + 1] = e0.y;
        X[a * 4 + 2] = e1.x; X[a * 4 + 3] = e1.y;
      }
#pragma unroll
      for (int i = 0; i < 16; ++i) asm volatile("" : "+v"(X[i]));
#pragma unroll
      for (int c = 0; c < 6; ++c) {
        const float bc = wsf[WS_B1S + c];
        float acc = 0.f;
#pragma unroll
        for (int di = 0; di < 2; ++di) {
#pragma unroll
          for (int dj = 0; dj < 2; ++dj) {
            float z = bc;
#pragma unroll
            for (int u = 0; u < 3; ++u)
#pragma unroll
              for (int v = 0; v < 3; ++v)
                z = fmaf(wsf[WS_W1S + c * 9 + u * 3 + v],
                         X[(di + u) * 4 + dj + v], z);
            acc += fmaxf(z, 0.f);
          }
        }
        pbase[c * POOL_CST + r * 6 + s] = acc;  // 0.25 pre-folded
      }
    }
  }
}

__device__ __forceinline__ void load6(const float* p, float r[6]) {
  const float2* q = reinterpret_cast<const float2*>(p);
  const float2 a = q[0], b = q[1], c = q[2];
  r[0] = a.x; r[1] = a.y; r[2] = b.x; r[3] = b.y; r[4] = c.x; r[5] = c.y;
}

// Channel-per-lane conv2, rolling 2-row stencil; weights read per-channel
// from LDS (broadcast) so only ~4 weight VGPRs are live at a time.
__device__ __forceinline__ void conv2_lane_lds(const float* pool,
                                               const float* w2L,
                                               const float* b2L,
                                               float yp[16]) {
  const int tid = threadIdx.x;
  const int imgl = tid >> 4, o = tid & 15;
  const float* pbase = pool + imgl * POOL_IST;

  const float yb = b2L[o];
#pragma unroll
  for (int p = 0; p < 16; ++p) yp[p] = yb;

#pragma unroll
  for (int c = 0; c < 6; ++c) {
    const float4 wv = *reinterpret_cast<const float4*>(w2L + o * 24 + c * 4);
    const float* pcb = pbase + c * POOL_CST;
    const float w00 = wv.x, w01 = wv.y, w10 = wv.z, w11 = wv.w;
    float r[2][6];
    load6(pcb, r[0]);
#pragma unroll
    for (int i2 = 0; i2 < 4; ++i2) {
      float* top = r[i2 & 1];
      float* bot = r[(i2 + 1) & 1];
      load6(pcb + (i2 + 1) * 6, bot);
#pragma unroll
      for (int j2 = 0; j2 < 4; ++j2) {
        float acc = yp[i2 * 4 + j2];
        acc = fmaf(w00, top[j2], acc);
        acc = fmaf(w01, top[j2 + 1], acc);
        acc = fmaf(w10, bot[j2], acc);
        acc = fmaf(w11, bot[j2 + 1], acc);
        yp[i2 * 4 + j2] = acc;
      }
    }
  }
}

// ------- Kernel A: x total-sum + 13 autocorrelations (grid-strided) -------
__global__ __launch_bounds__(256) void k_stats1(
    const float* __restrict__ x, float* ws, int nblk) {
  __shared__ __align__(16) float xl[XL_F];
  __shared__ float red[4][16];
  const int tid = threadIdx.x;
  zero_own_xl(xl);

  float T = 0.f, A[13];
#pragma unroll
  for (int i = 0; i < 13; ++i) A[i] = 0.f;

  int blk = blockIdx.x;
  float4 pfx;
  if (blk < nblk)
    pfx = reinterpret_cast<const float4*>(x)[(size_t)blk * 256 + tid];
  for (; blk < nblk; blk += gridDim.x) {
    WSYNC();                   // own-wave xl writes ordered
    write_interior(xl, pfx);
    const int bn = blk + gridDim.x;
    if (bn < nblk)
      pfx = reinterpret_cast<const float4*>(x)[(size_t)bn * 256 + tid];
    WSYNC();
    const float* ib = xl + (tid >> 4) * PST;
    const int l16 = tid & 15;
#pragma unroll
    for (int k = 0; k < 4; ++k) {
      const int p = l16 + k * 16;
      const int r = p >> 3, c = p & 7;
      const float* q = ib + (r + 2) * 12 + (c + 2);
      const float xc = q[0];
      T += xc;
      A[0]  = fmaf(xc, q[0],  A[0]);
      A[1]  = fmaf(xc, q[1],  A[1]);
      A[2]  = fmaf(xc, q[2],  A[2]);
      A[3]  = fmaf(xc, q[10], A[3]);
      A[4]  = fmaf(xc, q[11], A[4]);
      A[5]  = fmaf(xc, q[12], A[5]);
      A[6]  = fmaf(xc, q[13], A[6]);
      A[7]  = fmaf(xc, q[14], A[7]);
      A[8]  = fmaf(xc, q[22], A[8]);
      A[9]  = fmaf(xc, q[23], A[9]);
      A[10] = fmaf(xc, q[24], A[10]);
      A[11] = fmaf(xc, q[25], A[11]);
      A[12] = fmaf(xc, q[26], A[12]);
    }
  }

  const int wid = tid >> 6, lane = tid & 63;
#pragma unroll
  for (int i = 0; i < 14; ++i) {
    const float v = wave_sum(i == 0 ? T : A[i - 1]);
    if (lane == 0) red[wid][i] = v;
  }
  __syncthreads();             // cross-wave, once per block
  if (tid < 14) {
    const float tot = red[0][tid] + red[1][tid] + red[2][tid] + red[3][tid];
    atomicAdd(&ws[WS_T + tid], tot);
  }
}

// -------- fold1: closed-form BN1 stats -> folded conv1 weights ------------
__global__ void k_fold1(const float* __restrict__ g1,
                        const float* __restrict__ be1,
                        const float* __restrict__ w1,
                        const float* __restrict__ b1, float* ws, float NP) {
  const int c = threadIdx.x;
  if (c >= 6) return;
  float Av[13];
#pragma unroll
  for (int i = 0; i < 13; ++i) Av[i] = ws[WS_A + i];
  const float T = ws[WS_T];
  float w[9];
#pragma unroll
  for (int k = 0; k < 9; ++k) w[k] = w1[c * 9 + k];
  float sw = 0.f;
#pragma unroll
  for (int k = 0; k < 9; ++k) sw += w[k];
  float q2 = 0.f;
#pragma unroll
  for (int k1 = 0; k1 < 9; ++k1) {
    const int u1 = k1 / 3, v1 = k1 % 3;
#pragma unroll
    for (int k2 = 0; k2 < 9; ++k2) {
      int du = k2 / 3 - u1, dv = k2 % 3 - v1;
      if (du < 0 || (du == 0 && dv < 0)) { du = -du; dv = -dv; }
      const float a = (du == 0) ? Av[dv] : Av[3 + (du - 1) * 5 + dv + 2];
      q2 = fmaf(w[k1] * w[k2], a, q2);
    }
  }
  const float b = b1[c];
  const float sum1 = sw * T + NP * b;
  const float sumsq1 = q2 + 2.f * b * sw * T + NP * b * b;
  const float mean = sum1 / NP;
  const float var = sumsq1 / NP - mean * mean;
  const float sc = g1[c] * rsqrtf(var + 1e-5f);
  const float sh = be1[c] - mean * sc;
#pragma unroll
  for (int k = 0; k < 9; ++k)
    ws[WS_W1S + c * 9 + k] = w[k] * sc * 0.25f;        // pool 1/4 folded
  ws[WS_B1S + c] = fmaf(b, sc, sh) * 0.25f;
}

// -------- fold2: BN2 stats -> folded conv2 weights (w2s/b2s) ---------------
__global__ void k_fold2(const float* __restrict__ g2,
                        const float* __restrict__ be2,
                        const float* __restrict__ w2,
                        const float* __restrict__ b2, float* ws, float inv_n) {
  __shared__ float scs[16];
  const int t = threadIdx.x;
  if (t < 16) {
    const float mean = ws[WS_SUM2 + t] * inv_n;
    const float var  = ws[WS_SQ2 + t] * inv_n - mean * mean;
    const float sc   = g2[t] * rsqrtf(var + 1e-5f);
    const float sh   = be2[t] - mean * sc;
    scs[t] = sc;
    ws[WS_B2S + t] = fmaf(b2[t], sc, sh);
  }
  __syncthreads();
  if (t < 384) ws[WS_W2S + t] = w2[t] * scs[t / 24];
}

// ------- Kernel B: conv2 output statistics (grid-strided, wave-sync) -------
__global__ __launch_bounds__(256, 4) void k_stats2(
    const float* __restrict__ x, const float* __restrict__ w2,
    const float* __restrict__ b2, float* ws, int nblk) {
  __shared__ __align__(16) float xl[XL_F];
  __shared__ __align__(16) float pool[POOL_F];
  __shared__ __align__(16) float w2L[384];
  __shared__ float b2L[16];
  __shared__ float red[4][32];
  const int tid = threadIdx.x;
  for (int d = tid; d < 384; d += 256) w2L[d] = w2[d];
  if (tid < 16) b2L[tid] = b2[tid];
  zero_own_xl(xl);
  __syncthreads();             // weights visible to all waves

  float s = 0.f, q = 0.f;

  int t = blockIdx.x;
  float4 pfx;
  if (t < nblk)
    pfx = reinterpret_cast<const float4*>(x)[(size_t)t * 256 + tid];
  for (; t < nblk; t += gridDim.x) {
    WSYNC();                   // own-wave prior phase ordered
    write_interior(xl, pfx);
    const int tn = t + gridDim.x;
    if (tn < nblk)
      pfx = reinterpret_cast<const float4*>(x)[(size_t)tn * 256 + tid];
    WSYNC();
    pooled_front_coop(xl, pool, ws);
    WSYNC();
    float yp[16];
    conv2_lane_lds(pool, w2L, b2L, yp);
#pragma unroll
    for (int p = 0; p < 16; ++p) { s += yp[p]; q = fmaf(yp[p], yp[p], q); }
  }

  // reduce: across the 4 images of this wave, then across waves, one atomic
  s += __shfl_xor(s, 16, 64); s += __shfl_xor(s, 32, 64);
  q += __shfl_xor(q, 16, 64); q += __shfl_xor(q, 32, 64);
  const int wid = tid >> 6, lane = tid & 63;
  if (lane < 16) { red[wid][lane] = s; red[wid][16 + lane] = q; }
  __syncthreads();             // cross-wave, once per block
  if (tid < 32) {
    const float tot = red[0][tid] + red[1][tid] + red[2][tid] + red[3][tid];
    atomicAdd(&ws[tid < 16 ? WS_SUM2 + tid : WS_SQ2 + tid - 16], tot);
  }
}

// ---------------- Kernel C: full forward (grid-strided, wave-sync) ---------
// LDS = 30720 B caps residency at 5 blocks/CU; no min-waves hint (natural
// ~72 VGPR, no spill). Tail aliases each image's dead pooled map.
__global__ __launch_bounds__(256) void k_final(
    const float* __restrict__ x, const float* __restrict__ fw1,
    const float* __restrict__ fb1, const float* __restrict__ fw2,
    const float* __restrict__ fb2, const float* __restrict__ fw3,
    const float* __restrict__ fb3, const float* __restrict__ ws,
    float* __restrict__ out, int nblk) {
  __shared__ __align__(16) float xl[XL_F];
  __shared__ __align__(16) float pool[POOL_F];
  __shared__ __align__(16) float fw1L[FW1_F];  // [a][k], row stride 68
  __shared__ __align__(16) float w2L[384];
  __shared__ float b2L[16];

  const int tid = threadIdx.x;
  for (int d = tid; d < 1920; d += 256) {
    const int a = d >> 6, k = d & 63;
    fw1L[a * FW1_ST + k] = fw1[d];
  }
  for (int d = tid; d < 384; d += 256) w2L[d] = ws[WS_W2S + d];
  if (tid < 16) b2L[tid] = ws[WS_B2S + tid];
  zero_own_xl(xl);
  __syncthreads();             // once per block: weights + pad visible

  const int imgl = tid >> 4, al = tid & 15;
  const bool has2 = (al + 16) < 30;
  const float* ra = fw1L + al * FW1_ST;
  const float* rb = fw1L + (has2 ? (al + 16) * FW1_ST : 0);
  const float fb1a = fb1[al];
  const float fb1b = has2 ? fb1[al + 16] : 0.f;
  const float fb2a = (al < 15) ? fb2[al] : 0.f;
  const float fb3a = (al < 10) ? fb3[al] : 0.f;

  int t = blockIdx.x;
  float4 pfx;
  if (t < nblk)
    pfx = reinterpret_cast<const float4*>(x)[(size_t)t * 256 + tid];
  for (; t < nblk; t += gridDim.x) {
    WSYNC();                   // prior tile's tail LDS ops done
    write_interior(xl, pfx);
    const int tn = t + gridDim.x;
    if (tn < nblk)
      pfx = reinterpret_cast<const float4*>(x)[(size_t)tn * 256 + tid];
    WSYNC();
    pooled_front_coop(xl, pool, ws);
    WSYNC();
    float zp[16];
    conv2_lane_lds(pool, w2L, b2L, zp);

    float* ib = pool + imgl * POOL_IST;  // dead pooled map -> tail buffer

    // BN2 (folded) + ReLU + meanpool2 -> h at [0,64)
    float hq[4] = {0.f, 0.f, 0.f, 0.f};
#pragma unroll
    for (int i2 = 0; i2 < 4; ++i2)
#pragma unroll
      for (int j2 = 0; j2 < 4; ++j2)
        hq[(i2 >> 1) * 2 + (j2 >> 1)] += fmaxf(zp[i2 * 4 + j2], 0.f);
    float4 hv4;
    hv4.x = 0.25f * hq[0]; hv4.y = 0.25f * hq[1];
    hv4.z = 0.25f * hq[2]; hv4.w = 0.25f * hq[3];
    *reinterpret_cast<float4*>(ib + al * 4) = hv4;
    WSYNC();

    // FC1: lane al computes outputs {al, al+16}; weights from LDS rows
    float acc0 = fb1a;
    float acc1 = fb1b;
#pragma unroll
    for (int kk = 0; kk < 16; ++kk) {
      const float4 hv = *reinterpret_cast<const float4*>(ib + kk * 4);
      const float4 wa = *reinterpret_cast<const float4*>(ra + kk * 4);
      const float4 wb = *reinterpret_cast<const float4*>(rb + kk * 4);
      acc0 = fmaf(wa.x, hv.x, acc0); acc0 = fmaf(wa.y, hv.y, acc0);
      acc0 = fmaf(wa.z, hv.z, acc0); acc0 = fmaf(wa.w, hv.w, acc0);
      acc1 = fmaf(wb.x, hv.x, acc1); acc1 = fmaf(wb.y, hv.y, acc1);
      acc1 = fmaf(wb.w, hv.w, acc1); acc1 = fmaf(wb.z, hv.z, acc1);
    }
    ib[68 + al] = fmaxf(acc0, 0.f);                  // a1 at [68,98)
    if (has2) ib[68 + al + 16] = fmaxf(acc1, 0.f);
    WSYNC();

    // FC2 -> a2 at [101,116)  (fully unrolled, weights from global/L1)
    if (al < 15) {
      float acc = fb2a;
#pragma unroll
      for (int j = 0; j < 30; ++j)
        acc = fmaf(fw2[al * 30 + j], ib[68 + j], acc);
      ib[101 + al] = fmaxf(acc, 0.f);
    }
    WSYNC();

    // FC3 + store
    if (al < 10) {
      float acc = fb3a;
#pragma unroll
      for (int j = 0; j < 15; ++j)
        acc = fmaf(fw3[al * 15 + j], ib[101 + j], acc);
      out[(size_t)(t * 16 + imgl) * 10 + al] = acc;
    }
  }
}

extern "C" void kernel_launch(void* const* d_in, const int* in_sizes, int n_in,
                              void* d_out, int out_size, void* d_ws, size_t ws_size,
                              hipStream_t stream) {
  (void)n_in; (void)out_size; (void)ws_size;
  const float* x   = (const float*)d_in[0];
  const float* w1  = (const float*)d_in[1];
  const float* b1  = (const float*)d_in[2];
  const float* g1  = (const float*)d_in[3];
  const float* be1 = (const float*)d_in[4];
  const float* w2  = (const float*)d_in[5];
  const float* b2  = (const float*)d_in[6];
  const float* g2  = (const float*)d_in[7];
  const float* be2 = (const float*)d_in[8];
  const float* fw1 = (const float*)d_in[9];
  const float* fb1 = (const float*)d_in[10];
  const float* fw2 = (const float*)d_in[11];
  const float* fb2 = (const float*)d_in[12];
  const float* fw3 = (const float*)d_in[13];
  const float* fb3 = (const float*)d_in[14];
  float* out = (float*)d_out;
  float* ws  = (float*)d_ws;

  const int Btot = in_sizes[0] / 64;  // 131072; % 16 == 0
  const int nblk = Btot / 16;         // 8192
  const float NP1 = (float)Btot * 100.0f;
  const float inv_n2 = 1.0f / ((float)Btot * 16.0f);
  const int grid = nblk < 1024 ? nblk : 1024;    // stats: measured-best
  const int kf_grid = nblk < 2048 ? nblk : 2048; // k_final: 4 tiles/block

  hipMemsetAsync(ws, 0, WS_ZERO_N * sizeof(float), stream);

  k_stats1<<<grid, 256, 0, stream>>>(x, ws, nblk);
  k_fold1<<<1, 64, 0, stream>>>(g1, be1, w1, b1, ws, NP1);
  k_stats2<<<grid, 256, 0, stream>>>(x, w2, b2, ws, nblk);
  k_fold2<<<1, 512, 0, stream>>>(g2, be2, w2, b2, ws, inv_n2);
  k_final<<<kf_grid, 256, 0, stream>>>(x, fw1, fb1, fw2, fb2, fw3, fb3, ws,
                                       out, nblk);
}